// Round 1
// 370.854 us; speedup vs baseline: 1.0162x; 1.0162x over previous
//
#include <hip/hip_runtime.h>
#include <cstdint>

typedef unsigned short u16;
using bf16x8 = __attribute__((ext_vector_type(8))) __bf16;
using f32x4  = __attribute__((ext_vector_type(4))) float;
typedef u16 u16x8 __attribute__((ext_vector_type(8)));

#define T_TOK 16384   // B * N_OBJ
#define E_NUM 8

__device__ __forceinline__ u16 f2bf(float f) {
    union { float f; unsigned u; } v; v.f = f;
    unsigned r = (v.u + 0x7FFFu + ((v.u >> 16) & 1u)) >> 16;
    return (u16)r;
}

__device__ __forceinline__ void gload_lds16(const void* g, void* l) {
    __builtin_amdgcn_global_load_lds(
        (const __attribute__((address_space(1))) void*)g,
        (__attribute__((address_space(3))) void*)l, 16, 0, 0);
}

// ---------------- prep: W (E,1024,1024) f32 -> WT (E,1024,1024) bf16 transposed ----------------
__global__ __launch_bounds__(256) void k_transpose(const float* __restrict__ W, u16* __restrict__ WT) {
    __shared__ float tile[32][33];
    int e = blockIdx.z;
    int d0 = blockIdx.x << 5, h0 = blockIdx.y << 5;
    int tx = threadIdx.x & 31, ty = threadIdx.x >> 5;   // 32x8
    const size_t eo = (size_t)e << 20;
#pragma unroll
    for (int i = 0; i < 4; ++i) {
        int r = ty + i * 8;
        tile[r][tx] = W[eo + (size_t)(d0 + r) * 1024 + h0 + tx];
    }
    __syncthreads();
#pragma unroll
    for (int i = 0; i < 4; ++i) {
        int r = ty + i * 8;
        WT[eo + (size_t)(h0 + r) * 1024 + d0 + tx] = f2bf(tile[tx][r]);
    }
}

// ---------------- router: exact fp32 logits, top-2; writes per-token info; folds x->bf16 ----------------
__global__ __launch_bounds__(256) void k_router(const float* __restrict__ x, const float* __restrict__ Wr,
                                                const float* __restrict__ br,
                                                int* __restrict__ tinfo, float* __restrict__ c1arr,
                                                u16* __restrict__ xbf) {
    const int wave = threadIdx.x >> 6, lane = threadIdx.x & 63;
    const int t = (blockIdx.x << 2) + wave;
    const float* xr = x + (size_t)t * 1024;
    u16* xbr = xbf + (size_t)t * 1024;
    float acc[8] = {0, 0, 0, 0, 0, 0, 0, 0};
#pragma unroll
    for (int i = 0; i < 16; ++i) {
        int d = (i << 6) + lane;
        float xv = xr[d];
        xbr[d] = f2bf(xv);
        float4 w0 = *(const float4*)(Wr + d * 8);
        float4 w1 = *(const float4*)(Wr + d * 8 + 4);
        acc[0] += xv * w0.x; acc[1] += xv * w0.y; acc[2] += xv * w0.z; acc[3] += xv * w0.w;
        acc[4] += xv * w1.x; acc[5] += xv * w1.y; acc[6] += xv * w1.z; acc[7] += xv * w1.w;
    }
#pragma unroll
    for (int off = 32; off > 0; off >>= 1)
#pragma unroll
        for (int e = 0; e < 8; ++e) acc[e] += __shfl_xor(acc[e], off);

    if (lane == 0) {
        float v1 = -1e30f, v2 = -1e30f; int i1 = 0, i2 = 0;
#pragma unroll
        for (int e = 0; e < 8; ++e) {
            float v = acc[e] + br[e];
            if (v > v1) { v2 = v1; i2 = i1; v1 = v; i1 = e; }
            else if (v > v2) { v2 = v; i2 = e; }
        }
        float c1 = 1.f / (1.f + expf(v2 - v1));
        tinfo[t] = i1 | (i2 << 4);
        c1arr[t] = c1;
    }
}

// ---------------- scatter: LDS histogram -> per-block base -> 8 per-expert lists ----------------
// top1 and top2 assignments of the same expert share one list (expert id is all the
// GEMM needs); halves ragged-tile padding vs 16 slots. i1 != i2 always, so the two
// atomicAdds of one token never collide on the same counter.
__global__ __launch_bounds__(1024) void k_scatter(const int* __restrict__ tinfo, const float* __restrict__ c1arr,
                                                  int* __restrict__ cnt, int* __restrict__ tok,
                                                  float* __restrict__ coef) {
    __shared__ int lcnt[8];
    __shared__ int lbase[8];
    const int tid = threadIdx.x;
    const int t = blockIdx.x * 1024 + tid;
    if (tid < 8) lcnt[tid] = 0;
    __syncthreads();
    int info = tinfo[t];
    float c1 = c1arr[t];
    int g1 = info & 15;
    int g2 = (info >> 4) & 15;
    int o1 = atomicAdd(&lcnt[g1], 1);
    int o2 = atomicAdd(&lcnt[g2], 1);
    __syncthreads();
    if (tid < 8) lbase[tid] = atomicAdd(cnt + tid, lcnt[tid]);
    __syncthreads();
    int p1 = lbase[g1] + o1;
    tok[(g1 << 14) + p1] = t; coef[(g1 << 14) + p1] = c1;
    int p2 = lbase[g2] + o2;
    tok[(g2 << 14) + p2] = t; coef[(g2 << 14) + p2] = 1.f - c1;
}

// ---------------- grouped GEMM, 128x128 tile, BK=64, single-buffer 2-barrier (m97 schedule) ----------------
// 4 waves, per-wave 64x64 output -> acc[4][4] (64 VGPR). 32 MFMA per wave per K-step
// between the two barriers (vs 16 in the previous 128x64 version) -> amortizes the
// vmcnt(0)+barrier drain; m97 ladder measures 874-912 TF at this exact config.
// PHASE 0: h = relu(gather(xbf) @ W1T + b1) -> hbuf (bf16)
// PHASE 1: out[tok] += coef * (hbuf @ W2T + b2)   (atomicAdd, out pre-zeroed)
template <int PHASE>
__global__ __launch_bounds__(256, 3) void k_gemm(
    const int* __restrict__ cnt, const int* __restrict__ tok, const float* __restrict__ coef,
    const u16* __restrict__ xbf, const u16* __restrict__ w1t, const u16* __restrict__ w2t,
    const float* __restrict__ b1, const float* __restrict__ b2,
    u16* __restrict__ hbuf, float* __restrict__ out)
{
    __shared__ u16 a_s[128 * 64];   // 16 KB
    __shared__ u16 b_s[128 * 64];   // 16 KB
    __shared__ int s_cnt[8];
    __shared__ int tok_s[128];
    __shared__ float coef_s[128];

    const int tid = threadIdx.x;
    if (tid < 8) s_cnt[tid] = cnt[tid];
    __syncthreads();

    // XCD-aware remap (bijective: 2112 = 8*264): each XCD owns 264 consecutive
    // linear tiles; each row-tile sweeps all 8 column-tiles -> A-tile L2 reuse.
    int bid = blockIdx.x + blockIdx.y * 264;            // hw flat id, 2112 total
    int lin = (bid & 7) * 264 + (bid >> 3);
    int xt = lin >> 3, yt = lin & 7;

    // uniform scan: which (group, tile) is this block?
    int g = -1, tile = 0, r0 = 0, mt = xt, rb = 0;
    for (int gg = 0; gg < 8; ++gg) {
        int c = s_cnt[gg], tg = (c + 127) >> 7;
        if (g < 0) {
            if (mt < tg) { g = gg; tile = mt; r0 = rb + (mt << 7); }
            else mt -= tg;
        }
        rb += c;
    }
    if (g < 0) return;
    const int cntg = s_cnt[g];
    const int e = g;
    const int nb = yt << 7;
    const int rowlim = cntg - (tile << 7);

    if (tid < 128) {
        int idx = (tile << 7) + tid;
        bool valid = idx < cntg;
        tok_s[tid] = valid ? tok[(g << 14) + idx] : 0;
        coef_s[tid] = valid ? coef[(g << 14) + idx] : 0.f;
    }
    __syncthreads();

    const int w = tid >> 6, l = tid & 63;
    const int wrow = (w >> 1) << 6, wcol = (w & 1) << 6;
    const u16* asrc = (PHASE == 0) ? xbf : hbuf;
    const u16* bsrc = (PHASE == 0) ? w1t : w2t;
    const size_t brow0 = ((size_t)e << 10) + nb;

    // T2 swizzle: LDS stays linear for global_load_lds; global SOURCE column is
    // pre-XORed so a swizzled ds_read returns the unswizzled element.
    const int sw = ((l & 7) ^ (l >> 3)) << 3;   // staging source col offset (elements)
    const int xk = (l & 7) << 3;                // read col XOR key (row&7 == l&7 for frag rows)

    // staging pointers: A = 4 slots x (32 rows/slot), B = 4 slots
    const u16* aptr[4]; int ldsa[4];
#pragma unroll
    for (int j = 0; j < 4; ++j) {
        int row = (j << 5) + (w << 3) + (l >> 3);
        int arow = (PHASE == 0) ? tok_s[row] : (r0 + row);
        aptr[j] = asrc + ((size_t)arow << 10) + sw;
        ldsa[j] = ((j << 5) + (w << 3)) * 64;
    }
    const u16* bptr[4]; int ldsb[4];
#pragma unroll
    for (int j = 0; j < 4; ++j) {
        int brow = (j << 5) + (w << 3) + (l >> 3);
        bptr[j] = bsrc + (brow0 + brow) * 1024 + sw;
        ldsb[j] = ((j << 5) + (w << 3)) * 64;
    }

    f32x4 acc[4][4];
#pragma unroll
    for (int mi = 0; mi < 4; ++mi)
#pragma unroll
        for (int ni = 0; ni < 4; ++ni) { acc[mi][ni][0] = 0.f; acc[mi][ni][1] = 0.f; acc[mi][ni][2] = 0.f; acc[mi][ni][3] = 0.f; }

    for (int kc = 0; kc < 16; ++kc) {
        const int ko = kc << 6;
#pragma unroll
        for (int j = 0; j < 4; ++j) gload_lds16(aptr[j] + ko, &a_s[ldsa[j]]);
#pragma unroll
        for (int j = 0; j < 4; ++j) gload_lds16(bptr[j] + ko, &b_s[ldsb[j]]);
        __syncthreads();
#pragma unroll
        for (int ks = 0; ks < 64; ks += 32) {
            const int co = (ks + ((l >> 4) << 3)) ^ xk;
            bf16x8 af[4], bfr[4];
#pragma unroll
            for (int mi = 0; mi < 4; ++mi)
                af[mi] = *(const bf16x8*)&a_s[(wrow + (mi << 4) + (l & 15)) * 64 + co];
#pragma unroll
            for (int ni = 0; ni < 4; ++ni)
                bfr[ni] = *(const bf16x8*)&b_s[(wcol + (ni << 4) + (l & 15)) * 64 + co];
#pragma unroll
            for (int mi = 0; mi < 4; ++mi)
#pragma unroll
                for (int ni = 0; ni < 4; ++ni)
                    acc[mi][ni] = __builtin_amdgcn_mfma_f32_16x16x32_bf16(af[mi], bfr[ni], acc[mi][ni], 0, 0, 0);
        }
        __syncthreads();
    }

    const int rq = (l >> 4) << 2;
    const int cl = l & 15;
#pragma unroll
    for (int ni = 0; ni < 4; ++ni) {
        int ccol = wcol + (ni << 4) + cl;
        float bias = (PHASE == 0 ? b1 : b2)[((size_t)e << 10) + nb + ccol];
#pragma unroll
        for (int mi = 0; mi < 4; ++mi) {
            int rbase = wrow + (mi << 4) + rq;
#pragma unroll
            for (int j = 0; j < 4; ++j) {
                int r = rbase + j;
                if (r < rowlim) {
                    float v = acc[mi][ni][j] + bias;
                    if constexpr (PHASE == 0) {
                        v = fmaxf(v, 0.f);
                        hbuf[(size_t)(r0 + r) * 1024 + nb + ccol] = f2bf(v);
                    } else {
                        atomicAdd(out + ((size_t)tok_s[r] << 10) + nb + ccol, v * coef_s[r]);
                    }
                }
            }
        }
    }
}

// ---------------- insurance fallback (ws too small): slow but correct ----------------
__global__ __launch_bounds__(256) void k_naive(const float* __restrict__ x, const float* __restrict__ Wr,
    const float* __restrict__ br, const float* __restrict__ W1, const float* __restrict__ b1,
    const float* __restrict__ W2, const float* __restrict__ b2, float* __restrict__ out)
{
    __shared__ float xs[1024];
    __shared__ float hs[1024];
    __shared__ float red[4];
    __shared__ float lg[8];
    const int tid = threadIdx.x;
    const size_t t = blockIdx.x;
    for (int i = tid; i < 1024; i += 256) xs[i] = x[t * 1024 + i];
    __syncthreads();
    float lacc[8] = {0, 0, 0, 0, 0, 0, 0, 0};
    for (int d = tid; d < 1024; d += 256) {
        float xv = xs[d];
#pragma unroll
        for (int e = 0; e < 8; ++e) lacc[e] += xv * Wr[d * 8 + e];
    }
    for (int e = 0; e < 8; ++e) {
        float v = lacc[e];
        for (int off = 32; off > 0; off >>= 1) v += __shfl_xor(v, off);
        if ((tid & 63) == 0) red[tid >> 6] = v;
        __syncthreads();
        if (tid == 0) lg[e] = red[0] + red[1] + red[2] + red[3] + br[e];
        __syncthreads();
    }
    float v1 = -1e30f, v2 = -1e30f; int i1 = 0, i2 = 0;
    for (int e = 0; e < 8; ++e) {
        float v = lg[e];
        if (v > v1) { v2 = v1; i2 = i1; v1 = v; i1 = e; }
        else if (v > v2) { v2 = v; i2 = e; }
    }
    float c1 = 1.f / (1.f + expf(v2 - v1)), c2 = 1.f - c1;
    float yacc[4] = {0, 0, 0, 0};
    for (int slot = 0; slot < 2; ++slot) {
        int e = slot ? i2 : i1;
        float cw = slot ? c2 : c1;
        __syncthreads();
        float ha[4];
        for (int jb = 0; jb < 4; ++jb) {
            int j = (jb << 8) + tid;
            float a = b1[(e << 10) + j];
            for (int d = 0; d < 1024; ++d) a += xs[d] * W1[(((size_t)e << 10) + d) * 1024 + j];
            ha[jb] = fmaxf(a, 0.f);
        }
        for (int jb = 0; jb < 4; ++jb) hs[(jb << 8) + tid] = ha[jb];
        __syncthreads();
        for (int ob = 0; ob < 4; ++ob) {
            int o = (ob << 8) + tid;
            float a = b2[(e << 10) + o];
            for (int h = 0; h < 1024; ++h) a += hs[h] * W2[(((size_t)e << 10) + h) * 1024 + o];
            yacc[ob] += cw * a;
        }
    }
    for (int ob = 0; ob < 4; ++ob) out[t * 1024 + (ob << 8) + tid] = yacc[ob];
}

extern "C" void kernel_launch(void* const* d_in, const int* in_sizes, int n_in,
                              void* d_out, int out_size, void* d_ws, size_t ws_size,
                              hipStream_t stream) {
    const float* x  = (const float*)d_in[0];
    const float* Wr = (const float*)d_in[1];
    const float* br = (const float*)d_in[2];
    const float* W1 = (const float*)d_in[3];
    const float* b1 = (const float*)d_in[4];
    const float* W2 = (const float*)d_in[5];
    const float* b2 = (const float*)d_in[6];
    float* out = (float*)d_out;

    const size_t OFF_TOK   = (size_t)1 << 20;
    const size_t OFF_COEF  = (size_t)2 << 20;
    const size_t OFF_TINFO = (size_t)3 << 20;
    const size_t OFF_C1    = OFF_TINFO + (size_t)T_TOK * 4;
    const size_t OFF_XBF   = (size_t)4 << 20;
    const size_t OFF_W1T   = OFF_XBF + (size_t)T_TOK * 1024 * 2;          // +32MB
    const size_t OFF_W2T   = OFF_W1T + (size_t)E_NUM * 1024 * 1024 * 2;   // +16MB
    const size_t OFF_H     = OFF_W2T + (size_t)E_NUM * 1024 * 1024 * 2;   // +16MB
    const size_t WS_NEED   = OFF_H + (size_t)(2 * T_TOK + 128) * 1024 * 2; // h + pad

    if (ws_size < WS_NEED) {
        k_naive<<<T_TOK, 256, 0, stream>>>(x, Wr, br, W1, b1, W2, b2, out);
        return;
    }

    char* ws = (char*)d_ws;
    int*   cnt   = (int*)ws;
    int*   tok   = (int*)(ws + OFF_TOK);
    float* coef  = (float*)(ws + OFF_COEF);
    int*   tinfo = (int*)(ws + OFF_TINFO);
    float* c1arr = (float*)(ws + OFF_C1);
    u16*   xbf   = (u16*)(ws + OFF_XBF);
    u16*   w1t   = (u16*)(ws + OFF_W1T);
    u16*   w2t   = (u16*)(ws + OFF_W2T);
    u16*   hbuf  = (u16*)(ws + OFF_H);

    hipMemsetAsync(cnt, 0, 64, stream);
    hipMemsetAsync(d_out, 0, (size_t)out_size * sizeof(float), stream);
    k_transpose<<<dim3(32, 32, 8), 256, 0, stream>>>(W1, w1t);
    k_transpose<<<dim3(32, 32, 8), 256, 0, stream>>>(W2, w2t);
    k_router<<<4096, 256, 0, stream>>>(x, Wr, br, tinfo, c1arr, xbf);
    k_scatter<<<16, 1024, 0, stream>>>(tinfo, c1arr, cnt, tok, coef);
    dim3 gg(264, 8);
    k_gemm<0><<<gg, 256, 0, stream>>>(cnt, tok, coef, xbf, w1t, w2t, b1, b2, hbuf, out);
    k_gemm<1><<<gg, 256, 0, stream>>>(cnt, tok, coef, xbf, w1t, w2t, b1, b2, hbuf, out);
}